// Round 9
// baseline (59.156 us; speedup 1.0000x reference)
//
#include <hip/hip_runtime.h>
#include <math.h>

#define D_IN  2048
#define D_OUT 8192

// Two rows per 256-thread block, software-pipelined one phase apart so every
// barrier region carries row-A work on one pipe and row-B work on another
// (VALU vs DS vs VMEM). Per-row arithmetic identical to the verified R7/R8
// kernel: ascending-h FWHT stages, exact lo+hi / lo-hi association.
//
// LDS float4 X4s[2560] (40 KB):
//   scrA [0:512)  scrB [512:1024)  A_A [1024:1536)  A_B [1536:2048)
//   exchange quarters at bases {0,512,1024,2048} (avoid live A_B in R3)
//
// DPP direction convention (GCN): row_ror:N => dst[i] = src[(i-N) mod 16].

#if __has_builtin(__builtin_amdgcn_permlane16_swap) && __has_builtin(__builtin_amdgcn_permlane32_swap)
#define HAVE_PLSWAP 1
#endif

template<int CTRL>
__device__ __forceinline__ float dpp_full(float x) {
  int xi = __float_as_int(x);
  return __int_as_float(__builtin_amdgcn_update_dpp(xi, xi, CTRL, 0xF, 0xF, true));
}
// partner across lane-xor-4: ror:4 feeds banks {1,3} (bit2=1), ror:12 feeds {0,2}
__device__ __forceinline__ float dpp_xor4(float x) {
  int xi = __float_as_int(x);
  int r = __builtin_amdgcn_update_dpp(0, xi, 0x124, 0xF, 0xA, false);  // ror:4  -> banks 1,3
  r     = __builtin_amdgcn_update_dpp(r,  xi, 0x12C, 0xF, 0x5, false); // ror:12 -> banks 0,2
  return __int_as_float(r);
}
__device__ __forceinline__ void bfly_pl16(float& A, float& B, float sgn) {
#ifdef HAVE_PLSWAP
  auto r0 = __builtin_amdgcn_permlane16_swap(__float_as_uint(A), __float_as_uint(B), false, false);
  float lo = __uint_as_float(r0[0]), hi = __uint_as_float(r0[1]);
  float s = lo + hi, d = lo - hi;
  auto r1 = __builtin_amdgcn_permlane16_swap(__float_as_uint(s), __float_as_uint(d), false, false);
  A = __uint_as_float(r1[0]); B = __uint_as_float(r1[1]);
  (void)sgn;
#else
  float pA = __shfl_xor(A, 16, 64); A = fmaf(sgn, A, pA);
  float pB = __shfl_xor(B, 16, 64); B = fmaf(sgn, B, pB);
#endif
}
__device__ __forceinline__ void bfly_pl32(float& A, float& B, float sgn) {
#ifdef HAVE_PLSWAP
  auto r0 = __builtin_amdgcn_permlane32_swap(__float_as_uint(A), __float_as_uint(B), false, false);
  float lo = __uint_as_float(r0[0]), hi = __uint_as_float(r0[1]);
  float s = lo + hi, d = lo - hi;
  auto r1 = __builtin_amdgcn_permlane32_swap(__float_as_uint(s), __float_as_uint(d), false, false);
  A = __uint_as_float(r1[0]); B = __uint_as_float(r1[1]);
  (void)sgn;
#else
  float pA = __shfl_xor(A, 32, 64); A = fmaf(sgn, A, pA);
  float pB = __shfl_xor(B, 32, 64); B = fmaf(sgn, B, pB);
#endif
}

// h=1,2 on a float4 group, reference association
__device__ __forceinline__ void r4grp(float* g) {
  float y0 = g[0] + g[1], y1 = g[0] - g[1], y2 = g[2] + g[3], y3 = g[2] - g[3];
  g[0] = y0 + y2; g[2] = y0 - y2; g[1] = y1 + y3; g[3] = y1 - y3;
}
template<int N>
__device__ __forceinline__ void lane_stages(float* v, float sg1, float sg2, float sg4,
                                            float sg8, float sg16, float sg32) {
#pragma unroll
  for (int k = 0; k < N; ++k) { float p = dpp_full<0xB1>(v[k]);  v[k] = fmaf(sg1, v[k], p); }  // h=4
#pragma unroll
  for (int k = 0; k < N; ++k) { float p = dpp_full<0x4E>(v[k]);  v[k] = fmaf(sg2, v[k], p); }  // h=8
#pragma unroll
  for (int k = 0; k < N; ++k) { float p = dpp_xor4(v[k]);        v[k] = fmaf(sg4, v[k], p); }  // h=16
#pragma unroll
  for (int k = 0; k < N; ++k) { float p = dpp_full<0x128>(v[k]); v[k] = fmaf(sg8, v[k], p); }  // h=32
#pragma unroll
  for (int k = 0; k < N; k += 2) bfly_pl16(v[k], v[k+1], sg16);                                // h=64
#pragma unroll
  for (int k = 0; k < N; k += 2) bfly_pl32(v[k], v[k+1], sg32);                                // h=128
}
template<int NQ>
__device__ __forceinline__ void reg_stages(float* v) {
#pragma unroll
  for (int b = 1; b < NQ; b <<= 1)
#pragma unroll
    for (int q = 0; q < NQ; ++q) if (!(q & b))
#pragma unroll
      for (int c = 0; c < 4; ++c) {
        float lo = v[4*q+c], hi = v[4*(q|b)+c];
        v[4*q+c] = lo + hi; v[4*(q|b)+c] = lo - hi;
      }
}
__device__ __forceinline__ void comb4(float* vq, float4 b4, float4 c4, float4 d4,
                                      float s0w, float s1w) {
  float pB[4] = {b4.x, b4.y, b4.z, b4.w};
  float pC[4] = {c4.x, c4.y, c4.z, c4.w};
  float pD[4] = {d4.x, d4.y, d4.z, d4.w};
#pragma unroll
  for (int c = 0; c < 4; ++c) {
    float um = fmaf(s0w, vq[c], pB[c]);
    float uo = fmaf(s0w, pC[c], pD[c]);
    vq[c] = fmaf(s1w, um, uo);
  }
}
__device__ __forceinline__ int exqb(int w) { return (w == 3) ? 2048 : (w << 9); }

__global__ __launch_bounds__(256, 4) void fastfood_kernel(
    const float* __restrict__ xg, const float* __restrict__ Bg,
    const float* __restrict__ Gg, const float* __restrict__ Sg,
    const int*   __restrict__ Pg, const float* __restrict__ Ug,
    float* __restrict__ outg)
{
  __shared__ float4 X4s[2560];   // 40 KB

  const int t = threadIdx.x, lane = t & 63, wave = t >> 6;
  const int rowA = 2 * blockIdx.x, rowB = rowA + 1;
  const float sg1  = (lane & 1)  ? -1.f : 1.f;
  const float sg2  = (lane & 2)  ? -1.f : 1.f;
  const float sg4  = (lane & 4)  ? -1.f : 1.f;
  const float sg8  = (lane & 8)  ? -1.f : 1.f;
  const float sg16 = (lane & 16) ? -1.f : 1.f;
  const float sg32 = (lane & 32) ? -1.f : 1.f;
  const float s0w  = (wave & 1) ? -1.f : 1.f;
  const float s1w  = (wave & 2) ? -1.f : 1.f;
  const float c1 = (float)(1.0 / (6.283185307179586 * 90.50966799187808)); // 1/(2*pi*sqrt(8192))
  const int4*   P4 = reinterpret_cast<const int4*>(Pg);
  const float4* G4 = reinterpret_cast<const float4*>(Gg);
  const float4* S4 = reinterpret_cast<const float4*>(Sg);
  const float4* U4 = reinterpret_cast<const float4*>(Ug);

  // ===== R0: load both rows' x, FWHT-2048 regs for A, write scrA =====
  float a[8], b8[8];
  {
    const float4* x4A = reinterpret_cast<const float4*>(xg + (size_t)rowA * D_IN);
    const float4* x4B = reinterpret_cast<const float4*>(xg + (size_t)rowB * D_IN);
    const float4* B4 = reinterpret_cast<const float4*>(Bg);
#pragma unroll
    for (int m = 0; m < 2; ++m) {
      int f = lane + 64 * m + 128 * wave;
      float4 bv = B4[f], xa = x4A[f], xb = x4B[f];
      a[4*m+0]  = xa.x * bv.x; a[4*m+1]  = xa.y * bv.y; a[4*m+2]  = xa.z * bv.z; a[4*m+3]  = xa.w * bv.w;
      b8[4*m+0] = xb.x * bv.x; b8[4*m+1] = xb.y * bv.y; b8[4*m+2] = xb.z * bv.z; b8[4*m+3] = xb.w * bv.w;
    }
  }
  r4grp(a); r4grp(a + 4);
  lane_stages<8>(a, sg1, sg2, sg4, sg8, sg16, sg32);
  reg_stages<2>(a);   // h=256
#pragma unroll
  for (int m = 0; m < 2; ++m)
    X4s[lane + 64 * m + 128 * wave] = make_float4(a[4*m], a[4*m+1], a[4*m+2], a[4*m+3]);
  __syncthreads();   // BAR1

  // ===== R1: combine A (h=512,1024) + A_A store  ||  FWHT-2048 regs B + scrB =====
#pragma unroll
  for (int m = 0; m < 2; ++m) {
    int fb = lane + 64 * m;
    comb4(a + 4*m, X4s[fb + 128 * (wave ^ 1)], X4s[fb + 128 * (wave ^ 2)],
          X4s[fb + 128 * (wave ^ 3)], s0w, s1w);
  }
#pragma unroll
  for (int m = 0; m < 2; ++m)
    X4s[1024 + lane + 64 * m + 128 * wave] = make_float4(a[4*m], a[4*m+1], a[4*m+2], a[4*m+3]);
  r4grp(b8); r4grp(b8 + 4);
  lane_stages<8>(b8, sg1, sg2, sg4, sg8, sg16, sg32);
  reg_stages<2>(b8);
#pragma unroll
  for (int m = 0; m < 2; ++m)
    X4s[512 + lane + 64 * m + 128 * wave] = make_float4(b8[4*m], b8[4*m+1], b8[4*m+2], b8[4*m+3]);
  __syncthreads();   // BAR2

  // ===== R2: gather A (DS+VMEM)  ||  combine B + A_B store =====
  float vA[32];
  {
    const float* a_f = reinterpret_cast<const float*>(X4s + 1024);
#pragma unroll
    for (int q = 0; q < 8; ++q) {
      int idx = lane + 64 * q + 512 * wave;
      int4 pp = P4[idx]; float4 gv = G4[idx];
      vA[4*q+0] = a_f[pp.x & (D_IN-1)] * gv.x;
      vA[4*q+1] = a_f[pp.y & (D_IN-1)] * gv.y;
      vA[4*q+2] = a_f[pp.z & (D_IN-1)] * gv.z;
      vA[4*q+3] = a_f[pp.w & (D_IN-1)] * gv.w;
    }
  }
#pragma unroll
  for (int m = 0; m < 2; ++m) {
    int fb = lane + 64 * m;
    comb4(b8 + 4*m, X4s[512 + fb + 128 * (wave ^ 1)], X4s[512 + fb + 128 * (wave ^ 2)],
          X4s[512 + fb + 128 * (wave ^ 3)], s0w, s1w);
  }
#pragma unroll
  for (int m = 0; m < 2; ++m)
    X4s[1536 + lane + 64 * m + 128 * wave] = make_float4(b8[4*m], b8[4*m+1], b8[4*m+2], b8[4*m+3]);
  __syncthreads();   // BAR3

  // ===== R3: gather B (DS+VMEM)  ||  FWHT-8192 regs A (VALU); then exchW A =====
  float vB[32];
  {
    const float* b_f = reinterpret_cast<const float*>(X4s + 1536);
#pragma unroll
    for (int q = 0; q < 8; ++q) {
      int idx = lane + 64 * q + 512 * wave;
      int4 pp = P4[idx]; float4 gv = G4[idx];
      vB[4*q+0] = b_f[pp.x & (D_IN-1)] * gv.x;
      vB[4*q+1] = b_f[pp.y & (D_IN-1)] * gv.y;
      vB[4*q+2] = b_f[pp.z & (D_IN-1)] * gv.z;
      vB[4*q+3] = b_f[pp.w & (D_IN-1)] * gv.w;
    }
  }
#pragma unroll
  for (int q = 0; q < 8; ++q) r4grp(vA + 4*q);
  lane_stages<32>(vA, sg1, sg2, sg4, sg8, sg16, sg32);
  reg_stages<8>(vA);   // h=256,512,1024
  {
    int eb = exqb(wave);
#pragma unroll
    for (int q = 0; q < 8; ++q)
      X4s[eb + lane + 64 * q] = make_float4(vA[4*q], vA[4*q+1], vA[4*q+2], vA[4*q+3]);
  }
  __syncthreads();   // BAR4

  // ===== R4: exchR+combine+epilogue A  ||  FWHT-8192 regs B =====
  {
    int e1 = exqb(wave ^ 1), e2 = exqb(wave ^ 2), e3 = exqb(wave ^ 3);
#pragma unroll
    for (int q = 0; q < 8; ++q) {
      int fb = lane + 64 * q;
      comb4(vA + 4*q, X4s[e1 + fb], X4s[e2 + fb], X4s[e3 + fb], s0w, s1w);
    }
    float4* out4 = reinterpret_cast<float4*>(outg + (size_t)rowA * D_OUT);
#pragma unroll
    for (int q = 0; q < 8; ++q) {
      int idx = lane + 64 * q + 512 * wave;
      float4 s4 = S4[idx], u4 = U4[idx], res;
      float rev;
      rev = fmaf(vA[4*q+0]*s4.x, c1, u4.x); rev -= rintf(rev); res.x = __builtin_amdgcn_cosf(rev) * 0.015625f;
      rev = fmaf(vA[4*q+1]*s4.y, c1, u4.y); rev -= rintf(rev); res.y = __builtin_amdgcn_cosf(rev) * 0.015625f;
      rev = fmaf(vA[4*q+2]*s4.z, c1, u4.z); rev -= rintf(rev); res.z = __builtin_amdgcn_cosf(rev) * 0.015625f;
      rev = fmaf(vA[4*q+3]*s4.w, c1, u4.w); rev -= rintf(rev); res.w = __builtin_amdgcn_cosf(rev) * 0.015625f;
      out4[idx] = res;
    }
  }
#pragma unroll
  for (int q = 0; q < 8; ++q) r4grp(vB + 4*q);
  lane_stages<32>(vB, sg1, sg2, sg4, sg8, sg16, sg32);
  reg_stages<8>(vB);
  __syncthreads();   // BAR5 (all exchR A done -> exchange reusable)

  // ===== R5: exchW B =====
  {
    int eb = exqb(wave);
#pragma unroll
    for (int q = 0; q < 8; ++q)
      X4s[eb + lane + 64 * q] = make_float4(vB[4*q], vB[4*q+1], vB[4*q+2], vB[4*q+3]);
  }
  __syncthreads();   // BAR6

  // ===== R6: exchR+combine+epilogue B =====
  {
    int e1 = exqb(wave ^ 1), e2 = exqb(wave ^ 2), e3 = exqb(wave ^ 3);
#pragma unroll
    for (int q = 0; q < 8; ++q) {
      int fb = lane + 64 * q;
      comb4(vB + 4*q, X4s[e1 + fb], X4s[e2 + fb], X4s[e3 + fb], s0w, s1w);
    }
    float4* out4 = reinterpret_cast<float4*>(outg + (size_t)rowB * D_OUT);
#pragma unroll
    for (int q = 0; q < 8; ++q) {
      int idx = lane + 64 * q + 512 * wave;
      float4 s4 = S4[idx], u4 = U4[idx], res;
      float rev;
      rev = fmaf(vB[4*q+0]*s4.x, c1, u4.x); rev -= rintf(rev); res.x = __builtin_amdgcn_cosf(rev) * 0.015625f;
      rev = fmaf(vB[4*q+1]*s4.y, c1, u4.y); rev -= rintf(rev); res.y = __builtin_amdgcn_cosf(rev) * 0.015625f;
      rev = fmaf(vB[4*q+2]*s4.z, c1, u4.z); rev -= rintf(rev); res.z = __builtin_amdgcn_cosf(rev) * 0.015625f;
      rev = fmaf(vB[4*q+3]*s4.w, c1, u4.w); rev -= rintf(rev); res.w = __builtin_amdgcn_cosf(rev) * 0.015625f;
      out4[idx] = res;
    }
  }
}

extern "C" void kernel_launch(void* const* d_in, const int* in_sizes, int n_in,
                              void* d_out, int out_size, void* d_ws, size_t ws_size,
                              hipStream_t stream) {
  const float* x = (const float*)d_in[0];
  const float* B = (const float*)d_in[1];
  const float* G = (const float*)d_in[2];
  const float* S = (const float*)d_in[3];
  const int*   P = (const int*)d_in[4];
  const float* U = (const float*)d_in[5];
  float* out = (float*)d_out;
  const int rows = in_sizes[0] / D_IN;  // 2048
  fastfood_kernel<<<rows / 2, 256, 0, stream>>>(x, B, G, S, P, U, out);
}

// Round 10
// 40.450 us; speedup vs baseline: 1.4624x; 1.4624x over previous
//
#include <hip/hip_runtime.h>
#include <math.h>

#define D_IN  2048
#define D_OUT 8192

// Two rows per 256-thread block, software-pipelined one phase apart so every
// barrier region carries row-A work on one pipe and row-B work on another
// (VALU vs DS vs VMEM). Per-row arithmetic identical to the verified R7/R8
// kernel: ascending-h FWHT stages, exact lo+hi / lo-hi association.
//
// LDS float4 X4s[2560] (40 KB):
//   scrA [0:512)  scrB [512:1024)  A_A [1024:1536)  A_B [1536:2048)
//   exchange quarters at bases {0,512,1024,2048} (avoid live A_B in R3)
//
// __launch_bounds__(256, 2): VGPR cap 256. (256,4) capped the allocator at 64
// VGPRs and spilled vA/vB to scratch (R9: WRITE_SIZE 153600 KB, 59 us).
//
// DPP direction convention (GCN): row_ror:N => dst[i] = src[(i-N) mod 16].

#if __has_builtin(__builtin_amdgcn_permlane16_swap) && __has_builtin(__builtin_amdgcn_permlane32_swap)
#define HAVE_PLSWAP 1
#endif

template<int CTRL>
__device__ __forceinline__ float dpp_full(float x) {
  int xi = __float_as_int(x);
  return __int_as_float(__builtin_amdgcn_update_dpp(xi, xi, CTRL, 0xF, 0xF, true));
}
// partner across lane-xor-4: ror:4 feeds banks {1,3} (bit2=1), ror:12 feeds {0,2}
__device__ __forceinline__ float dpp_xor4(float x) {
  int xi = __float_as_int(x);
  int r = __builtin_amdgcn_update_dpp(0, xi, 0x124, 0xF, 0xA, false);  // ror:4  -> banks 1,3
  r     = __builtin_amdgcn_update_dpp(r,  xi, 0x12C, 0xF, 0x5, false); // ror:12 -> banks 0,2
  return __int_as_float(r);
}
__device__ __forceinline__ void bfly_pl16(float& A, float& B, float sgn) {
#ifdef HAVE_PLSWAP
  auto r0 = __builtin_amdgcn_permlane16_swap(__float_as_uint(A), __float_as_uint(B), false, false);
  float lo = __uint_as_float(r0[0]), hi = __uint_as_float(r0[1]);
  float s = lo + hi, d = lo - hi;
  auto r1 = __builtin_amdgcn_permlane16_swap(__float_as_uint(s), __float_as_uint(d), false, false);
  A = __uint_as_float(r1[0]); B = __uint_as_float(r1[1]);
  (void)sgn;
#else
  float pA = __shfl_xor(A, 16, 64); A = fmaf(sgn, A, pA);
  float pB = __shfl_xor(B, 16, 64); B = fmaf(sgn, B, pB);
#endif
}
__device__ __forceinline__ void bfly_pl32(float& A, float& B, float sgn) {
#ifdef HAVE_PLSWAP
  auto r0 = __builtin_amdgcn_permlane32_swap(__float_as_uint(A), __float_as_uint(B), false, false);
  float lo = __uint_as_float(r0[0]), hi = __uint_as_float(r0[1]);
  float s = lo + hi, d = lo - hi;
  auto r1 = __builtin_amdgcn_permlane32_swap(__float_as_uint(s), __float_as_uint(d), false, false);
  A = __uint_as_float(r1[0]); B = __uint_as_float(r1[1]);
  (void)sgn;
#else
  float pA = __shfl_xor(A, 32, 64); A = fmaf(sgn, A, pA);
  float pB = __shfl_xor(B, 32, 64); B = fmaf(sgn, B, pB);
#endif
}

// h=1,2 on a float4 group, reference association
__device__ __forceinline__ void r4grp(float* g) {
  float y0 = g[0] + g[1], y1 = g[0] - g[1], y2 = g[2] + g[3], y3 = g[2] - g[3];
  g[0] = y0 + y2; g[2] = y0 - y2; g[1] = y1 + y3; g[3] = y1 - y3;
}
template<int N>
__device__ __forceinline__ void lane_stages(float* v, float sg1, float sg2, float sg4,
                                            float sg8, float sg16, float sg32) {
#pragma unroll
  for (int k = 0; k < N; ++k) { float p = dpp_full<0xB1>(v[k]);  v[k] = fmaf(sg1, v[k], p); }  // h=4
#pragma unroll
  for (int k = 0; k < N; ++k) { float p = dpp_full<0x4E>(v[k]);  v[k] = fmaf(sg2, v[k], p); }  // h=8
#pragma unroll
  for (int k = 0; k < N; ++k) { float p = dpp_xor4(v[k]);        v[k] = fmaf(sg4, v[k], p); }  // h=16
#pragma unroll
  for (int k = 0; k < N; ++k) { float p = dpp_full<0x128>(v[k]); v[k] = fmaf(sg8, v[k], p); }  // h=32
#pragma unroll
  for (int k = 0; k < N; k += 2) bfly_pl16(v[k], v[k+1], sg16);                                // h=64
#pragma unroll
  for (int k = 0; k < N; k += 2) bfly_pl32(v[k], v[k+1], sg32);                                // h=128
}
template<int NQ>
__device__ __forceinline__ void reg_stages(float* v) {
#pragma unroll
  for (int b = 1; b < NQ; b <<= 1)
#pragma unroll
    for (int q = 0; q < NQ; ++q) if (!(q & b))
#pragma unroll
      for (int c = 0; c < 4; ++c) {
        float lo = v[4*q+c], hi = v[4*(q|b)+c];
        v[4*q+c] = lo + hi; v[4*(q|b)+c] = lo - hi;
      }
}
__device__ __forceinline__ void comb4(float* vq, float4 b4, float4 c4, float4 d4,
                                      float s0w, float s1w) {
  float pB[4] = {b4.x, b4.y, b4.z, b4.w};
  float pC[4] = {c4.x, c4.y, c4.z, c4.w};
  float pD[4] = {d4.x, d4.y, d4.z, d4.w};
#pragma unroll
  for (int c = 0; c < 4; ++c) {
    float um = fmaf(s0w, vq[c], pB[c]);
    float uo = fmaf(s0w, pC[c], pD[c]);
    vq[c] = fmaf(s1w, um, uo);
  }
}
__device__ __forceinline__ int exqb(int w) { return (w == 3) ? 2048 : (w << 9); }

__global__ __launch_bounds__(256, 2) void fastfood_kernel(
    const float* __restrict__ xg, const float* __restrict__ Bg,
    const float* __restrict__ Gg, const float* __restrict__ Sg,
    const int*   __restrict__ Pg, const float* __restrict__ Ug,
    float* __restrict__ outg)
{
  __shared__ float4 X4s[2560];   // 40 KB

  const int t = threadIdx.x, lane = t & 63, wave = t >> 6;
  const int rowA = 2 * blockIdx.x, rowB = rowA + 1;
  const float sg1  = (lane & 1)  ? -1.f : 1.f;
  const float sg2  = (lane & 2)  ? -1.f : 1.f;
  const float sg4  = (lane & 4)  ? -1.f : 1.f;
  const float sg8  = (lane & 8)  ? -1.f : 1.f;
  const float sg16 = (lane & 16) ? -1.f : 1.f;
  const float sg32 = (lane & 32) ? -1.f : 1.f;
  const float s0w  = (wave & 1) ? -1.f : 1.f;
  const float s1w  = (wave & 2) ? -1.f : 1.f;
  const float c1 = (float)(1.0 / (6.283185307179586 * 90.50966799187808)); // 1/(2*pi*sqrt(8192))
  const int4*   P4 = reinterpret_cast<const int4*>(Pg);
  const float4* G4 = reinterpret_cast<const float4*>(Gg);
  const float4* S4 = reinterpret_cast<const float4*>(Sg);
  const float4* U4 = reinterpret_cast<const float4*>(Ug);

  // ===== R0: load both rows' x, FWHT-2048 regs for A, write scrA =====
  float a[8], b8[8];
  {
    const float4* x4A = reinterpret_cast<const float4*>(xg + (size_t)rowA * D_IN);
    const float4* x4B = reinterpret_cast<const float4*>(xg + (size_t)rowB * D_IN);
    const float4* B4 = reinterpret_cast<const float4*>(Bg);
#pragma unroll
    for (int m = 0; m < 2; ++m) {
      int f = lane + 64 * m + 128 * wave;
      float4 bv = B4[f], xa = x4A[f], xb = x4B[f];
      a[4*m+0]  = xa.x * bv.x; a[4*m+1]  = xa.y * bv.y; a[4*m+2]  = xa.z * bv.z; a[4*m+3]  = xa.w * bv.w;
      b8[4*m+0] = xb.x * bv.x; b8[4*m+1] = xb.y * bv.y; b8[4*m+2] = xb.z * bv.z; b8[4*m+3] = xb.w * bv.w;
    }
  }
  r4grp(a); r4grp(a + 4);
  lane_stages<8>(a, sg1, sg2, sg4, sg8, sg16, sg32);
  reg_stages<2>(a);   // h=256
#pragma unroll
  for (int m = 0; m < 2; ++m)
    X4s[lane + 64 * m + 128 * wave] = make_float4(a[4*m], a[4*m+1], a[4*m+2], a[4*m+3]);
  __syncthreads();   // BAR1

  // ===== R1: combine A (h=512,1024) + A_A store  ||  FWHT-2048 regs B + scrB =====
#pragma unroll
  for (int m = 0; m < 2; ++m) {
    int fb = lane + 64 * m;
    comb4(a + 4*m, X4s[fb + 128 * (wave ^ 1)], X4s[fb + 128 * (wave ^ 2)],
          X4s[fb + 128 * (wave ^ 3)], s0w, s1w);
  }
#pragma unroll
  for (int m = 0; m < 2; ++m)
    X4s[1024 + lane + 64 * m + 128 * wave] = make_float4(a[4*m], a[4*m+1], a[4*m+2], a[4*m+3]);
  r4grp(b8); r4grp(b8 + 4);
  lane_stages<8>(b8, sg1, sg2, sg4, sg8, sg16, sg32);
  reg_stages<2>(b8);
#pragma unroll
  for (int m = 0; m < 2; ++m)
    X4s[512 + lane + 64 * m + 128 * wave] = make_float4(b8[4*m], b8[4*m+1], b8[4*m+2], b8[4*m+3]);
  __syncthreads();   // BAR2

  // ===== R2: gather A (DS+VMEM)  ||  combine B + A_B store =====
  float vA[32];
  {
    const float* a_f = reinterpret_cast<const float*>(X4s + 1024);
#pragma unroll
    for (int q = 0; q < 8; ++q) {
      int idx = lane + 64 * q + 512 * wave;
      int4 pp = P4[idx]; float4 gv = G4[idx];
      vA[4*q+0] = a_f[pp.x & (D_IN-1)] * gv.x;
      vA[4*q+1] = a_f[pp.y & (D_IN-1)] * gv.y;
      vA[4*q+2] = a_f[pp.z & (D_IN-1)] * gv.z;
      vA[4*q+3] = a_f[pp.w & (D_IN-1)] * gv.w;
    }
  }
#pragma unroll
  for (int m = 0; m < 2; ++m) {
    int fb = lane + 64 * m;
    comb4(b8 + 4*m, X4s[512 + fb + 128 * (wave ^ 1)], X4s[512 + fb + 128 * (wave ^ 2)],
          X4s[512 + fb + 128 * (wave ^ 3)], s0w, s1w);
  }
#pragma unroll
  for (int m = 0; m < 2; ++m)
    X4s[1536 + lane + 64 * m + 128 * wave] = make_float4(b8[4*m], b8[4*m+1], b8[4*m+2], b8[4*m+3]);
  __syncthreads();   // BAR3

  // ===== R3: gather B (DS+VMEM)  ||  FWHT-8192 regs A (VALU); then exchW A =====
  float vB[32];
  {
    const float* b_f = reinterpret_cast<const float*>(X4s + 1536);
#pragma unroll
    for (int q = 0; q < 8; ++q) {
      int idx = lane + 64 * q + 512 * wave;
      int4 pp = P4[idx]; float4 gv = G4[idx];
      vB[4*q+0] = b_f[pp.x & (D_IN-1)] * gv.x;
      vB[4*q+1] = b_f[pp.y & (D_IN-1)] * gv.y;
      vB[4*q+2] = b_f[pp.z & (D_IN-1)] * gv.z;
      vB[4*q+3] = b_f[pp.w & (D_IN-1)] * gv.w;
    }
  }
#pragma unroll
  for (int q = 0; q < 8; ++q) r4grp(vA + 4*q);
  lane_stages<32>(vA, sg1, sg2, sg4, sg8, sg16, sg32);
  reg_stages<8>(vA);   // h=256,512,1024
  {
    int eb = exqb(wave);
#pragma unroll
    for (int q = 0; q < 8; ++q)
      X4s[eb + lane + 64 * q] = make_float4(vA[4*q], vA[4*q+1], vA[4*q+2], vA[4*q+3]);
  }
  __syncthreads();   // BAR4

  // ===== R4: exchR+combine+epilogue A  ||  FWHT-8192 regs B =====
  {
    int e1 = exqb(wave ^ 1), e2 = exqb(wave ^ 2), e3 = exqb(wave ^ 3);
#pragma unroll
    for (int q = 0; q < 8; ++q) {
      int fb = lane + 64 * q;
      comb4(vA + 4*q, X4s[e1 + fb], X4s[e2 + fb], X4s[e3 + fb], s0w, s1w);
    }
    float4* out4 = reinterpret_cast<float4*>(outg + (size_t)rowA * D_OUT);
#pragma unroll
    for (int q = 0; q < 8; ++q) {
      int idx = lane + 64 * q + 512 * wave;
      float4 s4 = S4[idx], u4 = U4[idx], res;
      float rev;
      rev = fmaf(vA[4*q+0]*s4.x, c1, u4.x); rev -= rintf(rev); res.x = __builtin_amdgcn_cosf(rev) * 0.015625f;
      rev = fmaf(vA[4*q+1]*s4.y, c1, u4.y); rev -= rintf(rev); res.y = __builtin_amdgcn_cosf(rev) * 0.015625f;
      rev = fmaf(vA[4*q+2]*s4.z, c1, u4.z); rev -= rintf(rev); res.z = __builtin_amdgcn_cosf(rev) * 0.015625f;
      rev = fmaf(vA[4*q+3]*s4.w, c1, u4.w); rev -= rintf(rev); res.w = __builtin_amdgcn_cosf(rev) * 0.015625f;
      out4[idx] = res;
    }
  }
#pragma unroll
  for (int q = 0; q < 8; ++q) r4grp(vB + 4*q);
  lane_stages<32>(vB, sg1, sg2, sg4, sg8, sg16, sg32);
  reg_stages<8>(vB);
  __syncthreads();   // BAR5 (all exchR A done -> exchange reusable)

  // ===== R5: exchW B =====
  {
    int eb = exqb(wave);
#pragma unroll
    for (int q = 0; q < 8; ++q)
      X4s[eb + lane + 64 * q] = make_float4(vB[4*q], vB[4*q+1], vB[4*q+2], vB[4*q+3]);
  }
  __syncthreads();   // BAR6

  // ===== R6: exchR+combine+epilogue B =====
  {
    int e1 = exqb(wave ^ 1), e2 = exqb(wave ^ 2), e3 = exqb(wave ^ 3);
#pragma unroll
    for (int q = 0; q < 8; ++q) {
      int fb = lane + 64 * q;
      comb4(vB + 4*q, X4s[e1 + fb], X4s[e2 + fb], X4s[e3 + fb], s0w, s1w);
    }
    float4* out4 = reinterpret_cast<float4*>(outg + (size_t)rowB * D_OUT);
#pragma unroll
    for (int q = 0; q < 8; ++q) {
      int idx = lane + 64 * q + 512 * wave;
      float4 s4 = S4[idx], u4 = U4[idx], res;
      float rev;
      rev = fmaf(vB[4*q+0]*s4.x, c1, u4.x); rev -= rintf(rev); res.x = __builtin_amdgcn_cosf(rev) * 0.015625f;
      rev = fmaf(vB[4*q+1]*s4.y, c1, u4.y); rev -= rintf(rev); res.y = __builtin_amdgcn_cosf(rev) * 0.015625f;
      rev = fmaf(vB[4*q+2]*s4.z, c1, u4.z); rev -= rintf(rev); res.z = __builtin_amdgcn_cosf(rev) * 0.015625f;
      rev = fmaf(vB[4*q+3]*s4.w, c1, u4.w); rev -= rintf(rev); res.w = __builtin_amdgcn_cosf(rev) * 0.015625f;
      out4[idx] = res;
    }
  }
}

extern "C" void kernel_launch(void* const* d_in, const int* in_sizes, int n_in,
                              void* d_out, int out_size, void* d_ws, size_t ws_size,
                              hipStream_t stream) {
  const float* x = (const float*)d_in[0];
  const float* B = (const float*)d_in[1];
  const float* G = (const float*)d_in[2];
  const float* S = (const float*)d_in[3];
  const int*   P = (const int*)d_in[4];
  const float* U = (const float*)d_in[5];
  float* out = (float*)d_out;
  const int rows = in_sizes[0] / D_IN;  // 2048
  fastfood_kernel<<<rows / 2, 256, 0, stream>>>(x, B, G, S, P, U, out);
}

// Round 11
// 25.752 us; speedup vs baseline: 2.2971x; 1.5708x over previous
//
#include <hip/hip_runtime.h>
#include <math.h>

#define D_IN  2048
#define D_OUT 8192

// One row per 256-thread block (4 waves) — R8 champion structure with two
// additive changes (no arithmetic change):
//  1. P/G table loads issued at kernel start (hoisted above the barriers the
//     compiler can't move them across) so their L2 latency hides under the
//     FWHT-2048 compute instead of serializing the gather phase.
//  2. Non-temporal output stores (write-once data; keeps tables/x resident
//     in L2/L3 instead of being flushed by 64 MB of streaming writes).
//
// LDS = single 32 KB buffer X:
//   [0:512)     float4: FWHT-2048 combine scratch
//   [1536:2048) float4: FWHT-2048 result "A" (live: store -> end of gather)
//   [0:2048)    float4: FWHT-8192 4-way exchange (written only after gather)
//
// DPP direction convention (GCN): row_ror:N => dst[i] = src[(i-N) mod 16].

#if __has_builtin(__builtin_amdgcn_permlane16_swap) && __has_builtin(__builtin_amdgcn_permlane32_swap)
#define HAVE_PLSWAP 1
#endif

typedef float f32x4 __attribute__((ext_vector_type(4)));

template<int CTRL>
__device__ __forceinline__ float dpp_full(float x) {
  int xi = __float_as_int(x);
  return __int_as_float(__builtin_amdgcn_update_dpp(xi, xi, CTRL, 0xF, 0xF, true));
}
// partner across lane-xor-4: ror:4 feeds banks {1,3} (bit2=1), ror:12 feeds {0,2}
__device__ __forceinline__ float dpp_xor4(float x) {
  int xi = __float_as_int(x);
  int r = __builtin_amdgcn_update_dpp(0, xi, 0x124, 0xF, 0xA, false);  // ror:4  -> banks 1,3
  r     = __builtin_amdgcn_update_dpp(r,  xi, 0x12C, 0xF, 0x5, false); // ror:12 -> banks 0,2
  return __int_as_float(r);
}
__device__ __forceinline__ void bfly_pl16(float& A, float& B, float sgn) {
#ifdef HAVE_PLSWAP
  auto r0 = __builtin_amdgcn_permlane16_swap(__float_as_uint(A), __float_as_uint(B), false, false);
  float lo = __uint_as_float(r0[0]), hi = __uint_as_float(r0[1]);
  float s = lo + hi, d = lo - hi;
  auto r1 = __builtin_amdgcn_permlane16_swap(__float_as_uint(s), __float_as_uint(d), false, false);
  A = __uint_as_float(r1[0]); B = __uint_as_float(r1[1]);
  (void)sgn;
#else
  float pA = __shfl_xor(A, 16, 64); A = fmaf(sgn, A, pA);
  float pB = __shfl_xor(B, 16, 64); B = fmaf(sgn, B, pB);
#endif
}
__device__ __forceinline__ void bfly_pl32(float& A, float& B, float sgn) {
#ifdef HAVE_PLSWAP
  auto r0 = __builtin_amdgcn_permlane32_swap(__float_as_uint(A), __float_as_uint(B), false, false);
  float lo = __uint_as_float(r0[0]), hi = __uint_as_float(r0[1]);
  float s = lo + hi, d = lo - hi;
  auto r1 = __builtin_amdgcn_permlane32_swap(__float_as_uint(s), __float_as_uint(d), false, false);
  A = __uint_as_float(r1[0]); B = __uint_as_float(r1[1]);
  (void)sgn;
#else
  float pA = __shfl_xor(A, 32, 64); A = fmaf(sgn, A, pA);
  float pB = __shfl_xor(B, 32, 64); B = fmaf(sgn, B, pB);
#endif
}

__global__ __launch_bounds__(256) void fastfood_kernel(
    const float* __restrict__ xg, const float* __restrict__ Bg,
    const float* __restrict__ Gg, const float* __restrict__ Sg,
    const int*   __restrict__ Pg, const float* __restrict__ Ug,
    float* __restrict__ outg)
{
  __shared__ float4 X4s[D_OUT / 4];   // 32 KB single buffer (see layout above)

  const int t = threadIdx.x, lane = t & 63, wave = t >> 6;
  const int row = blockIdx.x;
  const float sg1  = (lane & 1)  ? -1.f : 1.f;
  const float sg2  = (lane & 2)  ? -1.f : 1.f;
  const float sg4  = (lane & 4)  ? -1.f : 1.f;
  const float sg8  = (lane & 8)  ? -1.f : 1.f;
  const float sg16 = (lane & 16) ? -1.f : 1.f;
  const float sg32 = (lane & 32) ? -1.f : 1.f;
  // 4-way combine signs: u_m = fmaf(s0, own, pB); u_o = fmaf(s0, pC, pD);
  //                      res = fmaf(s1, u_m, u_o)
  const float s0w = (wave & 1) ? -1.f : 1.f;
  const float s1w = (wave & 2) ? -1.f : 1.f;

  // ===== FWHT-2048 of B*x, distributed: d = c | lane<<2 | m<<8 | wave<<9 =====
  float a[8];   // a[4m+c]
  {
    const float4* x4 = reinterpret_cast<const float4*>(xg + (size_t)row * D_IN);
    const float4* B4 = reinterpret_cast<const float4*>(Bg);
#pragma unroll
    for (int m = 0; m < 2; ++m) {
      int f = lane + 64 * m + 128 * wave;
      float4 xv = x4[f], bv = B4[f];
      a[4*m+0] = xv.x * bv.x; a[4*m+1] = xv.y * bv.y;
      a[4*m+2] = xv.z * bv.z; a[4*m+3] = xv.w * bv.w;
    }
  }
  // Prefetch permutation + Gaussian scale (independent of all barriers; issue
  // now so the ~200-cycle L2 latency hides under the FWHT-2048 compute).
  int4   pp[8];
  float4 gv[8];
  {
    const int4*   P4 = reinterpret_cast<const int4*>(Pg);
    const float4* G4 = reinterpret_cast<const float4*>(Gg);
#pragma unroll
    for (int q = 0; q < 8; ++q) {
      int idx = lane + 64 * q + 512 * wave;
      pp[q] = P4[idx];
      gv[q] = G4[idx];
    }
  }
#pragma unroll
  for (int m = 0; m < 2; ++m) {                                   // h=1,2
    float x0=a[4*m],x1=a[4*m+1],x2=a[4*m+2],x3=a[4*m+3];
    float y0=x0+x1,y1=x0-x1,y2=x2+x3,y3=x2-x3;
    a[4*m]=y0+y2; a[4*m+2]=y0-y2; a[4*m+1]=y1+y3; a[4*m+3]=y1-y3;
  }
#pragma unroll
  for (int k = 0; k < 8; ++k) { float p = dpp_full<0xB1>(a[k]);  a[k] = fmaf(sg1, a[k], p); }   // h=4
#pragma unroll
  for (int k = 0; k < 8; ++k) { float p = dpp_full<0x4E>(a[k]);  a[k] = fmaf(sg2, a[k], p); }   // h=8
#pragma unroll
  for (int k = 0; k < 8; ++k) { float p = dpp_xor4(a[k]);        a[k] = fmaf(sg4, a[k], p); }   // h=16
#pragma unroll
  for (int k = 0; k < 8; ++k) { float p = dpp_full<0x128>(a[k]); a[k] = fmaf(sg8, a[k], p); }   // h=32
#pragma unroll
  for (int k = 0; k < 8; k += 2) bfly_pl16(a[k], a[k+1], sg16);                                 // h=64
#pragma unroll
  for (int k = 0; k < 8; k += 2) bfly_pl32(a[k], a[k+1], sg32);                                 // h=128
#pragma unroll
  for (int c = 0; c < 4; ++c) {                                   // h=256 (m bit)
    float lo = a[c], hi = a[4+c];
    a[c] = lo + hi; a[4+c] = lo - hi;
  }
  // h=512,1024: 4-way cross-wave combine via scratch X[0:512)
#pragma unroll
  for (int m = 0; m < 2; ++m)
    X4s[lane + 64 * m + 128 * wave] = make_float4(a[4*m], a[4*m+1], a[4*m+2], a[4*m+3]);
  __syncthreads();   // #1 scratch ready
#pragma unroll
  for (int m = 0; m < 2; ++m) {
    int fb = lane + 64 * m;
    float4 B4v = X4s[fb + 128 * (wave ^ 1)];
    float4 C4v = X4s[fb + 128 * (wave ^ 2)];
    float4 D4v = X4s[fb + 128 * (wave ^ 3)];
    float pB[4] = {B4v.x, B4v.y, B4v.z, B4v.w};
    float pC[4] = {C4v.x, C4v.y, C4v.z, C4v.w};
    float pD[4] = {D4v.x, D4v.y, D4v.z, D4v.w};
#pragma unroll
    for (int c = 0; c < 4; ++c) {
      float um = fmaf(s0w, a[4*m+c], pB[c]);
      float uo = fmaf(s0w, pC[c], pD[c]);
      a[4*m+c] = fmaf(s1w, um, uo);
    }
  }
  // store final FWHT-2048 into A = X[1536:2048) (disjoint from scratch [0:512))
#pragma unroll
  for (int m = 0; m < 2; ++m)
    X4s[1536 + lane + 64 * m + 128 * wave] = make_float4(a[4*m], a[4*m+1], a[4*m+2], a[4*m+3]);
  __syncthreads();   // #2 A ready

  // ===== gather + Gaussian scale: o = c | lane<<2 | q<<8 | wave<<11 =====
  float v[32];
  {
    const float* a_f = reinterpret_cast<const float*>(X4s + 1536);
#pragma unroll
    for (int q = 0; q < 8; ++q) {
      v[4*q+0] = a_f[pp[q].x & (D_IN-1)] * gv[q].x;
      v[4*q+1] = a_f[pp[q].y & (D_IN-1)] * gv[q].y;
      v[4*q+2] = a_f[pp[q].z & (D_IN-1)] * gv[q].z;
      v[4*q+3] = a_f[pp[q].w & (D_IN-1)] * gv[q].w;
    }
  }

  // ===== FWHT-8192: h=1,2 (reg), h=4..128 (lane), h=256..1024 (q) =====
#pragma unroll
  for (int q = 0; q < 8; ++q) {
    float x0=v[4*q],x1=v[4*q+1],x2=v[4*q+2],x3=v[4*q+3];
    float y0=x0+x1,y1=x0-x1,y2=x2+x3,y3=x2-x3;
    v[4*q]=y0+y2; v[4*q+2]=y0-y2; v[4*q+1]=y1+y3; v[4*q+3]=y1-y3;
  }
#pragma unroll
  for (int k = 0; k < 32; ++k) { float p = dpp_full<0xB1>(v[k]);  v[k] = fmaf(sg1, v[k], p); }  // h=4
#pragma unroll
  for (int k = 0; k < 32; ++k) { float p = dpp_full<0x4E>(v[k]);  v[k] = fmaf(sg2, v[k], p); }  // h=8
#pragma unroll
  for (int k = 0; k < 32; ++k) { float p = dpp_xor4(v[k]);        v[k] = fmaf(sg4, v[k], p); }  // h=16
#pragma unroll
  for (int k = 0; k < 32; ++k) { float p = dpp_full<0x128>(v[k]); v[k] = fmaf(sg8, v[k], p); }  // h=32
#pragma unroll
  for (int k = 0; k < 32; k += 2) bfly_pl16(v[k], v[k+1], sg16);                                // h=64
#pragma unroll
  for (int k = 0; k < 32; k += 2) bfly_pl32(v[k], v[k+1], sg32);                                // h=128
#pragma unroll
  for (int b = 1; b < 8; b <<= 1)                                                               // h=256,512,1024
#pragma unroll
    for (int q = 0; q < 8; ++q) if (!(q & b))
#pragma unroll
      for (int c = 0; c < 4; ++c) {
        float lo = v[4*q+c], hi = v[4*(q|b)+c];
        v[4*q+c] = lo + hi; v[4*(q|b)+c] = lo - hi;
      }

  __syncthreads();   // #3 gather reads of A complete -> X fully reusable

  // ===== h=2048,4096: 4-way cross-wave combine via X (full 32 KB) =====
#pragma unroll
  for (int q = 0; q < 8; ++q)
    X4s[lane + 64 * q + 512 * wave] = make_float4(v[4*q], v[4*q+1], v[4*q+2], v[4*q+3]);
  __syncthreads();   // #4 exchange ready
#pragma unroll
  for (int q = 0; q < 8; ++q) {
    int fb = lane + 64 * q;
    float4 B4v = X4s[fb + 512 * (wave ^ 1)];
    float4 C4v = X4s[fb + 512 * (wave ^ 2)];
    float4 D4v = X4s[fb + 512 * (wave ^ 3)];
    float pB[4] = {B4v.x, B4v.y, B4v.z, B4v.w};
    float pC[4] = {C4v.x, C4v.y, C4v.z, C4v.w};
    float pD[4] = {D4v.x, D4v.y, D4v.z, D4v.w};
#pragma unroll
    for (int c = 0; c < 4; ++c) {
      float um = fmaf(s0w, v[4*q+c], pB[c]);
      float uo = fmaf(s0w, pC[c], pD[c]);
      v[4*q+c] = fmaf(s1w, um, uo);
    }
  }

  // ===== epilogue: cos(Vx + 2*pi*U) * sqrt(2/O), non-temporal stores =====
  {
    const float c1 = (float)(1.0 / (6.283185307179586 * 90.50966799187808)); // 1/(2*pi*sqrt(8192))
    const float4* S4 = reinterpret_cast<const float4*>(Sg);
    const float4* U4 = reinterpret_cast<const float4*>(Ug);
    f32x4* out4 = reinterpret_cast<f32x4*>(outg + (size_t)row * D_OUT);
#pragma unroll
    for (int q = 0; q < 8; ++q) {
      int idx = lane + 64 * q + 512 * wave;
      float4 s4 = S4[idx], u4 = U4[idx];
      f32x4 res;
      float rev;
      rev = fmaf(v[4*q+0]*s4.x, c1, u4.x); rev -= rintf(rev); res[0] = __builtin_amdgcn_cosf(rev) * 0.015625f;
      rev = fmaf(v[4*q+1]*s4.y, c1, u4.y); rev -= rintf(rev); res[1] = __builtin_amdgcn_cosf(rev) * 0.015625f;
      rev = fmaf(v[4*q+2]*s4.z, c1, u4.z); rev -= rintf(rev); res[2] = __builtin_amdgcn_cosf(rev) * 0.015625f;
      rev = fmaf(v[4*q+3]*s4.w, c1, u4.w); rev -= rintf(rev); res[3] = __builtin_amdgcn_cosf(rev) * 0.015625f;
      __builtin_nontemporal_store(res, &out4[idx]);
    }
  }
}

extern "C" void kernel_launch(void* const* d_in, const int* in_sizes, int n_in,
                              void* d_out, int out_size, void* d_ws, size_t ws_size,
                              hipStream_t stream) {
  const float* x = (const float*)d_in[0];
  const float* B = (const float*)d_in[1];
  const float* G = (const float*)d_in[2];
  const float* S = (const float*)d_in[3];
  const int*   P = (const int*)d_in[4];
  const float* U = (const float*)d_in[5];
  float* out = (float*)d_out;
  const int rows = in_sizes[0] / D_IN;  // 2048
  fastfood_kernel<<<rows, 256, 0, stream>>>(x, B, G, S, P, U, out);
}

// Round 12
// 25.677 us; speedup vs baseline: 2.3039x; 1.0029x over previous
//
#include <hip/hip_runtime.h>
#include <math.h>

#define D_IN  2048
#define D_OUT 8192

// One row per 256-thread block (4 waves) — R11 champion structure with one
// additional pure-reorder change:
//  3. S/U epilogue-table loads issued immediately after barrier #4, so their
//     L2/L3 latency hides under the exchange-read + combine phase instead of
//     serializing against the final NT stores. (pp/gv die at the gather, so
//     s4/u4 reuse those register slots; peak VGPR ~unchanged.)
// Carried from R11: P/G prefetch at kernel start; non-temporal output stores.
//
// LDS = single 32 KB buffer X:
//   [0:512)     float4: FWHT-2048 combine scratch
//   [1536:2048) float4: FWHT-2048 result "A" (live: store -> end of gather)
//   [0:2048)    float4: FWHT-8192 4-way exchange (written only after gather)
//
// DPP direction convention (GCN): row_ror:N => dst[i] = src[(i-N) mod 16].

#if __has_builtin(__builtin_amdgcn_permlane16_swap) && __has_builtin(__builtin_amdgcn_permlane32_swap)
#define HAVE_PLSWAP 1
#endif

typedef float f32x4 __attribute__((ext_vector_type(4)));

template<int CTRL>
__device__ __forceinline__ float dpp_full(float x) {
  int xi = __float_as_int(x);
  return __int_as_float(__builtin_amdgcn_update_dpp(xi, xi, CTRL, 0xF, 0xF, true));
}
// partner across lane-xor-4: ror:4 feeds banks {1,3} (bit2=1), ror:12 feeds {0,2}
__device__ __forceinline__ float dpp_xor4(float x) {
  int xi = __float_as_int(x);
  int r = __builtin_amdgcn_update_dpp(0, xi, 0x124, 0xF, 0xA, false);  // ror:4  -> banks 1,3
  r     = __builtin_amdgcn_update_dpp(r,  xi, 0x12C, 0xF, 0x5, false); // ror:12 -> banks 0,2
  return __int_as_float(r);
}
__device__ __forceinline__ void bfly_pl16(float& A, float& B, float sgn) {
#ifdef HAVE_PLSWAP
  auto r0 = __builtin_amdgcn_permlane16_swap(__float_as_uint(A), __float_as_uint(B), false, false);
  float lo = __uint_as_float(r0[0]), hi = __uint_as_float(r0[1]);
  float s = lo + hi, d = lo - hi;
  auto r1 = __builtin_amdgcn_permlane16_swap(__float_as_uint(s), __float_as_uint(d), false, false);
  A = __uint_as_float(r1[0]); B = __uint_as_float(r1[1]);
  (void)sgn;
#else
  float pA = __shfl_xor(A, 16, 64); A = fmaf(sgn, A, pA);
  float pB = __shfl_xor(B, 16, 64); B = fmaf(sgn, B, pB);
#endif
}
__device__ __forceinline__ void bfly_pl32(float& A, float& B, float sgn) {
#ifdef HAVE_PLSWAP
  auto r0 = __builtin_amdgcn_permlane32_swap(__float_as_uint(A), __float_as_uint(B), false, false);
  float lo = __uint_as_float(r0[0]), hi = __uint_as_float(r0[1]);
  float s = lo + hi, d = lo - hi;
  auto r1 = __builtin_amdgcn_permlane32_swap(__float_as_uint(s), __float_as_uint(d), false, false);
  A = __uint_as_float(r1[0]); B = __uint_as_float(r1[1]);
  (void)sgn;
#else
  float pA = __shfl_xor(A, 32, 64); A = fmaf(sgn, A, pA);
  float pB = __shfl_xor(B, 32, 64); B = fmaf(sgn, B, pB);
#endif
}

__global__ __launch_bounds__(256) void fastfood_kernel(
    const float* __restrict__ xg, const float* __restrict__ Bg,
    const float* __restrict__ Gg, const float* __restrict__ Sg,
    const int*   __restrict__ Pg, const float* __restrict__ Ug,
    float* __restrict__ outg)
{
  __shared__ float4 X4s[D_OUT / 4];   // 32 KB single buffer (see layout above)

  const int t = threadIdx.x, lane = t & 63, wave = t >> 6;
  const int row = blockIdx.x;
  const float sg1  = (lane & 1)  ? -1.f : 1.f;
  const float sg2  = (lane & 2)  ? -1.f : 1.f;
  const float sg4  = (lane & 4)  ? -1.f : 1.f;
  const float sg8  = (lane & 8)  ? -1.f : 1.f;
  const float sg16 = (lane & 16) ? -1.f : 1.f;
  const float sg32 = (lane & 32) ? -1.f : 1.f;
  // 4-way combine signs: u_m = fmaf(s0, own, pB); u_o = fmaf(s0, pC, pD);
  //                      res = fmaf(s1, u_m, u_o)
  const float s0w = (wave & 1) ? -1.f : 1.f;
  const float s1w = (wave & 2) ? -1.f : 1.f;

  // ===== FWHT-2048 of B*x, distributed: d = c | lane<<2 | m<<8 | wave<<9 =====
  float a[8];   // a[4m+c]
  {
    const float4* x4 = reinterpret_cast<const float4*>(xg + (size_t)row * D_IN);
    const float4* B4 = reinterpret_cast<const float4*>(Bg);
#pragma unroll
    for (int m = 0; m < 2; ++m) {
      int f = lane + 64 * m + 128 * wave;
      float4 xv = x4[f], bv = B4[f];
      a[4*m+0] = xv.x * bv.x; a[4*m+1] = xv.y * bv.y;
      a[4*m+2] = xv.z * bv.z; a[4*m+3] = xv.w * bv.w;
    }
  }
  // Prefetch permutation + Gaussian scale (independent of all barriers; issue
  // now so the ~200-cycle L2 latency hides under the FWHT-2048 compute).
  int4   pp[8];
  float4 gv[8];
  {
    const int4*   P4 = reinterpret_cast<const int4*>(Pg);
    const float4* G4 = reinterpret_cast<const float4*>(Gg);
#pragma unroll
    for (int q = 0; q < 8; ++q) {
      int idx = lane + 64 * q + 512 * wave;
      pp[q] = P4[idx];
      gv[q] = G4[idx];
    }
  }
#pragma unroll
  for (int m = 0; m < 2; ++m) {                                   // h=1,2
    float x0=a[4*m],x1=a[4*m+1],x2=a[4*m+2],x3=a[4*m+3];
    float y0=x0+x1,y1=x0-x1,y2=x2+x3,y3=x2-x3;
    a[4*m]=y0+y2; a[4*m+2]=y0-y2; a[4*m+1]=y1+y3; a[4*m+3]=y1-y3;
  }
#pragma unroll
  for (int k = 0; k < 8; ++k) { float p = dpp_full<0xB1>(a[k]);  a[k] = fmaf(sg1, a[k], p); }   // h=4
#pragma unroll
  for (int k = 0; k < 8; ++k) { float p = dpp_full<0x4E>(a[k]);  a[k] = fmaf(sg2, a[k], p); }   // h=8
#pragma unroll
  for (int k = 0; k < 8; ++k) { float p = dpp_xor4(a[k]);        a[k] = fmaf(sg4, a[k], p); }   // h=16
#pragma unroll
  for (int k = 0; k < 8; ++k) { float p = dpp_full<0x128>(a[k]); a[k] = fmaf(sg8, a[k], p); }   // h=32
#pragma unroll
  for (int k = 0; k < 8; k += 2) bfly_pl16(a[k], a[k+1], sg16);                                 // h=64
#pragma unroll
  for (int k = 0; k < 8; k += 2) bfly_pl32(a[k], a[k+1], sg32);                                 // h=128
#pragma unroll
  for (int c = 0; c < 4; ++c) {                                   // h=256 (m bit)
    float lo = a[c], hi = a[4+c];
    a[c] = lo + hi; a[4+c] = lo - hi;
  }
  // h=512,1024: 4-way cross-wave combine via scratch X[0:512)
#pragma unroll
  for (int m = 0; m < 2; ++m)
    X4s[lane + 64 * m + 128 * wave] = make_float4(a[4*m], a[4*m+1], a[4*m+2], a[4*m+3]);
  __syncthreads();   // #1 scratch ready
#pragma unroll
  for (int m = 0; m < 2; ++m) {
    int fb = lane + 64 * m;
    float4 B4v = X4s[fb + 128 * (wave ^ 1)];
    float4 C4v = X4s[fb + 128 * (wave ^ 2)];
    float4 D4v = X4s[fb + 128 * (wave ^ 3)];
    float pB[4] = {B4v.x, B4v.y, B4v.z, B4v.w};
    float pC[4] = {C4v.x, C4v.y, C4v.z, C4v.w};
    float pD[4] = {D4v.x, D4v.y, D4v.z, D4v.w};
#pragma unroll
    for (int c = 0; c < 4; ++c) {
      float um = fmaf(s0w, a[4*m+c], pB[c]);
      float uo = fmaf(s0w, pC[c], pD[c]);
      a[4*m+c] = fmaf(s1w, um, uo);
    }
  }
  // store final FWHT-2048 into A = X[1536:2048) (disjoint from scratch [0:512))
#pragma unroll
  for (int m = 0; m < 2; ++m)
    X4s[1536 + lane + 64 * m + 128 * wave] = make_float4(a[4*m], a[4*m+1], a[4*m+2], a[4*m+3]);
  __syncthreads();   // #2 A ready

  // ===== gather + Gaussian scale: o = c | lane<<2 | q<<8 | wave<<11 =====
  float v[32];
  {
    const float* a_f = reinterpret_cast<const float*>(X4s + 1536);
#pragma unroll
    for (int q = 0; q < 8; ++q) {
      v[4*q+0] = a_f[pp[q].x & (D_IN-1)] * gv[q].x;
      v[4*q+1] = a_f[pp[q].y & (D_IN-1)] * gv[q].y;
      v[4*q+2] = a_f[pp[q].z & (D_IN-1)] * gv[q].z;
      v[4*q+3] = a_f[pp[q].w & (D_IN-1)] * gv[q].w;
    }
  }

  // ===== FWHT-8192: h=1,2 (reg), h=4..128 (lane), h=256..1024 (q) =====
#pragma unroll
  for (int q = 0; q < 8; ++q) {
    float x0=v[4*q],x1=v[4*q+1],x2=v[4*q+2],x3=v[4*q+3];
    float y0=x0+x1,y1=x0-x1,y2=x2+x3,y3=x2-x3;
    v[4*q]=y0+y2; v[4*q+2]=y0-y2; v[4*q+1]=y1+y3; v[4*q+3]=y1-y3;
  }
#pragma unroll
  for (int k = 0; k < 32; ++k) { float p = dpp_full<0xB1>(v[k]);  v[k] = fmaf(sg1, v[k], p); }  // h=4
#pragma unroll
  for (int k = 0; k < 32; ++k) { float p = dpp_full<0x4E>(v[k]);  v[k] = fmaf(sg2, v[k], p); }  // h=8
#pragma unroll
  for (int k = 0; k < 32; ++k) { float p = dpp_xor4(v[k]);        v[k] = fmaf(sg4, v[k], p); }  // h=16
#pragma unroll
  for (int k = 0; k < 32; ++k) { float p = dpp_full<0x128>(v[k]); v[k] = fmaf(sg8, v[k], p); }  // h=32
#pragma unroll
  for (int k = 0; k < 32; k += 2) bfly_pl16(v[k], v[k+1], sg16);                                // h=64
#pragma unroll
  for (int k = 0; k < 32; k += 2) bfly_pl32(v[k], v[k+1], sg32);                                // h=128
#pragma unroll
  for (int b = 1; b < 8; b <<= 1)                                                               // h=256,512,1024
#pragma unroll
    for (int q = 0; q < 8; ++q) if (!(q & b))
#pragma unroll
      for (int c = 0; c < 4; ++c) {
        float lo = v[4*q+c], hi = v[4*(q|b)+c];
        v[4*q+c] = lo + hi; v[4*(q|b)+c] = lo - hi;
      }

  __syncthreads();   // #3 gather reads of A complete -> X fully reusable

  // ===== h=2048,4096: 4-way cross-wave combine via X (full 32 KB) =====
#pragma unroll
  for (int q = 0; q < 8; ++q)
    X4s[lane + 64 * q + 512 * wave] = make_float4(v[4*q], v[4*q+1], v[4*q+2], v[4*q+3]);
  __syncthreads();   // #4 exchange ready

  // Prefetch S/U now (pp/gv are dead; their latency hides under the
  // exchange-read + combine below instead of stalling the final stores).
  float4 s4r[8], u4r[8];
  {
    const float4* S4 = reinterpret_cast<const float4*>(Sg);
    const float4* U4 = reinterpret_cast<const float4*>(Ug);
#pragma unroll
    for (int q = 0; q < 8; ++q) {
      int idx = lane + 64 * q + 512 * wave;
      s4r[q] = S4[idx];
      u4r[q] = U4[idx];
    }
  }

#pragma unroll
  for (int q = 0; q < 8; ++q) {
    int fb = lane + 64 * q;
    float4 B4v = X4s[fb + 512 * (wave ^ 1)];
    float4 C4v = X4s[fb + 512 * (wave ^ 2)];
    float4 D4v = X4s[fb + 512 * (wave ^ 3)];
    float pB[4] = {B4v.x, B4v.y, B4v.z, B4v.w};
    float pC[4] = {C4v.x, C4v.y, C4v.z, C4v.w};
    float pD[4] = {D4v.x, D4v.y, D4v.z, D4v.w};
#pragma unroll
    for (int c = 0; c < 4; ++c) {
      float um = fmaf(s0w, v[4*q+c], pB[c]);
      float uo = fmaf(s0w, pC[c], pD[c]);
      v[4*q+c] = fmaf(s1w, um, uo);
    }
  }

  // ===== epilogue: cos(Vx + 2*pi*U) * sqrt(2/O), non-temporal stores =====
  {
    const float c1 = (float)(1.0 / (6.283185307179586 * 90.50966799187808)); // 1/(2*pi*sqrt(8192))
    f32x4* out4 = reinterpret_cast<f32x4*>(outg + (size_t)row * D_OUT);
#pragma unroll
    for (int q = 0; q < 8; ++q) {
      int idx = lane + 64 * q + 512 * wave;
      float4 s4 = s4r[q], u4 = u4r[q];
      f32x4 res;
      float rev;
      rev = fmaf(v[4*q+0]*s4.x, c1, u4.x); rev -= rintf(rev); res[0] = __builtin_amdgcn_cosf(rev) * 0.015625f;
      rev = fmaf(v[4*q+1]*s4.y, c1, u4.y); rev -= rintf(rev); res[1] = __builtin_amdgcn_cosf(rev) * 0.015625f;
      rev = fmaf(v[4*q+2]*s4.z, c1, u4.z); rev -= rintf(rev); res[2] = __builtin_amdgcn_cosf(rev) * 0.015625f;
      rev = fmaf(v[4*q+3]*s4.w, c1, u4.w); rev -= rintf(rev); res[3] = __builtin_amdgcn_cosf(rev) * 0.015625f;
      __builtin_nontemporal_store(res, &out4[idx]);
    }
  }
}

extern "C" void kernel_launch(void* const* d_in, const int* in_sizes, int n_in,
                              void* d_out, int out_size, void* d_ws, size_t ws_size,
                              hipStream_t stream) {
  const float* x = (const float*)d_in[0];
  const float* B = (const float*)d_in[1];
  const float* G = (const float*)d_in[2];
  const float* S = (const float*)d_in[3];
  const int*   P = (const int*)d_in[4];
  const float* U = (const float*)d_in[5];
  float* out = (float*)d_out;
  const int rows = in_sizes[0] / D_IN;  // 2048
  fastfood_kernel<<<rows, 256, 0, stream>>>(x, B, G, S, P, U, out);
}